// Round 3
// baseline (684.630 us; speedup 1.0000x reference)
//
#include <hip/hip_runtime.h>

#define EPS 1e-6f
#define NSTEPS 4
#define TPB 64
#define TILES 2          // tiles (b,c images) per 1-wave block; 32 threads/tile
#define PITCH 33         // LDS row pitch (floats): (r+i)%32 bank map, 2-way max => free
#define TSTRIDE (32 * PITCH)

typedef float floatx4 __attribute__((ext_vector_type(4)));  // native vec: OK for nontemporal builtins

// ---------------------------------------------------------------------------
// Kernel 1: precompute Thomas coefficients per (step, c, solve-line).
// Layout split for register-cheap pipelining in the solver:
//   F*[((s*3+c)*32 + i)*32 + lane] = float2(a_i, 1/denom_i)   (forward sweep)
//   C*[((s*3+c)*32 + i)*32 + lane] = cs_i                     (backward sweep)
// lane = h (x-dir) or w (y-dir). float2 = 2 VGPR per hoisted element (vs 4
// for float4) -> compiler can software-pipeline the serial chain ~2x deeper.
// ---------------------------------------------------------------------------
__global__ void coeff_kernel(const float* __restrict__ ab,
                             const float* __restrict__ atc,
                             const float* __restrict__ bb,
                             const float* __restrict__ btc,
                             float2* __restrict__ FX,
                             float*  __restrict__ CX,
                             float2* __restrict__ FY,
                             float*  __restrict__ CY)
{
    int tid = blockIdx.x * blockDim.x + threadIdx.x;
    if (tid >= 768) return;                 // 2 dirs * 4 steps * 3 ch * 32 lanes
    int lane = tid & 31;
    int rest = tid >> 5;                    // 0..23
    int c    = rest % 3;
    int s    = (rest / 3) & 3;
    int dir  = rest / 12;                   // 0 = x, 1 = y
    float t  = 0.15f * (float)s;

    float A[32];
    float dt;
    if (dir == 0) {
        int h = lane;
        const float* pa = ab  + (c * 32 + h) * 32;
        const float* pt = atc + (c * 32 + h) * 32;
        #pragma unroll
        for (int w = 0; w < 32; w++)
            A[w] = fmaxf(pa[w] + t * pt[w], EPS);
        dt = 0.075f;                        // DT/2
    } else {
        int w = lane;
        #pragma unroll
        for (int h = 0; h < 32; h++)
            A[h] = fmaxf(bb[(c * 32 + h) * 32 + w] + t * btc[(c * 32 + h) * 32 + w], EPS);
        dt = 0.15f;                         // DT
    }

    // 3-tap mean with replicate padding
    float S[32];
    #pragma unroll
    for (int i = 0; i < 32; i++) {
        float l = A[(i == 0) ? 0 : i - 1];
        float r = A[(i == 31) ? 31 : i + 1];
        S[i] = (l + A[i] + r) / 3.0f;
    }

    float2* fdst = (dir == 0 ? FX : FY) + ((s * 3 + c) * 32) * 32 + lane;
    float*  cdst = (dir == 0 ? CX : CY) + ((s * 3 + c) * 32) * 32 + lane;
    float cp = 0.0f;
    for (int i = 0; i < 32; i++) {
        float co = S[i] * dt;               // coeff = smoothed * dt / DX^2 (DX=1)
        float a  = -co;
        float b  = (i == 0 || i == 31) ? (1.0f + co) : (1.0f + 2.0f * co);
        float cc = -co;
        float denom = (b - a * cp) + EPS;   // matches ref: eps added every step
        float inv = 1.0f / denom;           // precise division here (cheap)
        float cs  = cc / denom;
        if (i == 31) cs = 0.0f;             // ref zeroes c_star[N-1]
        fdst[i * 32] = make_float2(a, inv);
        cdst[i * 32] = cs;
        cp = cs;
    }
}

// ---------------------------------------------------------------------------
// Kernel 2: fully fused 4-step ADI pipeline. 1-wave (64-thread) blocks, 2
// tiles per block; tile lives in LDS across all 12 solves. x-phases: thread
// = row, serial over w. y-phases: thread = col, serial over h.
//
// R2 changes vs R1 (all arithmetic bitwise identical):
//  - csr[32] register array removed; backward sweep re-loads cs from the
//    split C* arrays (independent scalar loads, L1-hot, deeply hoistable).
//    Frees 32 VGPRs of chain-pipelining headroom.
//  - forward coefficients as float2 -> hoisting costs 2 regs/element not 4.
//  - 1-wave workgroups: __syncthreads() is intra-wave (near-free), LDS/block
//    8.4 KB no longer caps occupancy; VGPR is the only limiter.
// ---------------------------------------------------------------------------
__global__ __launch_bounds__(TPB, 4)
void diffuse_kernel(const float* __restrict__ u,
                    const float2* __restrict__ FX,
                    const float*  __restrict__ CX,
                    const float2* __restrict__ FY,
                    const float*  __restrict__ CY,
                    const float* __restrict__ coupling,
                    float* __restrict__ out)
{
    __shared__ float lds[TILES * TSTRIDE];

    const int tid = threadIdx.x;
    const int tl  = tid >> 5;               // tile within block (0..1)
    const int r   = tid & 31;               // lane within tile
    // consecutive blocks share c: co-resident blocks on a CU keep the same
    // coefficient slabs hot in L1
    const int nper = gridDim.x / 3;         // blocks per channel
    const int c    = blockIdx.x / nper;
    const long grp = blockIdx.x % nper;
    const long b0  = grp * TILES + tl;      // batch index of this tile
    const long base = (b0 * 3 + c) << 10;   // 32*32 floats per tile

    float* T = lds + tl * TSTRIDE;

    // ---- stage global -> LDS (coalesced float4 per half-wave) ----
    const float4* src4 = (const float4*)(u + base);
    #pragma unroll
    for (int j = 0; j < 8; j++) {
        float4 v = src4[j * 32 + r];
        int f = (j * 32 + r) * 4;           // linear float index in tile
        int row = f >> 5, col = f & 31;
        float* p = T + row * PITCH + col;
        p[0] = v.x; p[1] = v.y; p[2] = v.z; p[3] = v.w;
    }
    const float kc = coupling[c * 3 + c];
    __syncthreads();

    float val[32];

    #pragma unroll 1
    for (int s = 0; s < NSTEPS; s++) {
        const float2* fx = FX + (s * 3 + c) * 1024;
        const float*  cx = CX + (s * 3 + c) * 1024;
        const float2* fy = FY + (s * 3 + c) * 1024;
        const float*  cy = CY + (s * 3 + c) * 1024;

        // ---------- x half-step #1 (thread = row r) ----------
        {
            float dp = 0.0f;
            #pragma unroll
            for (int i = 0; i < 32; i++) {
                float2 p = fx[i * 32 + r];
                float d  = (s == 0) ? T[r * PITCH + i] : val[i];
                dp = (d - p.x * dp) * p.y;
                val[i] = dp;
            }
            float x = 0.0f;
            #pragma unroll
            for (int i = 31; i >= 0; i--) {
                x = val[i] - cx[i * 32 + r] * x;
                T[r * PITCH + i] = x;       // expose rows for y transpose
            }
        }
        __syncthreads();

        // ---------- y full step (thread = col r) ----------
        {
            float dp = 0.0f;
            #pragma unroll
            for (int i = 0; i < 32; i++) {
                float2 p = fy[i * 32 + r];
                float d  = T[i * PITCH + r];
                dp = (d - p.x * dp) * p.y;
                val[i] = dp;
            }
            float x = 0.0f;
            #pragma unroll
            for (int i = 31; i >= 0; i--) {
                x = val[i] - cy[i * 32 + r] * x;
                T[i * PITCH + r] = x;       // expose cols for x transpose
            }
        }
        __syncthreads();

        // ---------- x half-step #2 (thread = row r), result + scale in regs ----------
        {
            float dp = 0.0f;
            #pragma unroll
            for (int i = 0; i < 32; i++) {
                float2 p = fx[i * 32 + r];
                float d  = T[r * PITCH + i];
                dp = (d - p.x * dp) * p.y;
                val[i] = dp;
            }
            float x = 0.0f;
            #pragma unroll
            for (int i = 31; i >= 0; i--) {
                x = val[i] - cx[i * 32 + r] * x;  // backward uses UNSCALED neighbor
                val[i] = kc * x;            // channel-diagonal scale
            }
        }
        // no barrier needed: x2 and next x1 touch only this thread's row
    }

    // ---- write back: regs -> LDS rows -> coalesced global float4 ----
    #pragma unroll
    for (int i = 0; i < 32; i++) T[r * PITCH + i] = val[i];
    __syncthreads();

    floatx4* dst4 = (floatx4*)(out + base);
    #pragma unroll
    for (int j = 0; j < 8; j++) {
        int f = (j * 32 + r) * 4;
        int row = f >> 5, col = f & 31;
        float* p = T + row * PITCH + col;
        floatx4 v = { p[0], p[1], p[2], p[3] };
        __builtin_nontemporal_store(v, &dst4[j * 32 + r]);  // streaming out: don't evict u from LLC
    }
}

// ---------------------------------------------------------------------------
extern "C" void kernel_launch(void* const* d_in, const int* in_sizes, int n_in,
                              void* d_out, int out_size, void* d_ws, size_t ws_size,
                              hipStream_t stream) {
    const float* u   = (const float*)d_in[0];
    const float* ab  = (const float*)d_in[1];  // alpha_base
    const float* bb  = (const float*)d_in[2];  // beta_base
    const float* atc = (const float*)d_in[3];  // alpha_time_coeff
    const float* btc = (const float*)d_in[4];  // beta_time_coeff
    const float* cpl = (const float*)d_in[5];  // channel_coupling [3][3]
    float* out = (float*)d_out;

    // workspace: FX (96 KB) | CX (48 KB) | FY (96 KB) | CY (48 KB)
    const int NC = 4 * 3 * 32 * 32;            // 12288 coefficient entries
    float2* FX = (float2*)d_ws;
    float*  CX = (float*)(FX + NC);
    float2* FY = (float2*)(CX + NC);
    float*  CY = (float*)(FY + NC);

    coeff_kernel<<<3, 256, 0, stream>>>(ab, atc, bb, btc, FX, CX, FY, CY);

    int B = in_sizes[0] / (3 * 32 * 32);       // 16384
    int nblocks = (B / TILES) * 3;             // 24576 one-wave blocks
    diffuse_kernel<<<nblocks, TPB, 0, stream>>>(u, FX, CX, FY, CY, cpl, out);
}

// Round 4
// 456.129 us; speedup vs baseline: 1.5010x; 1.5010x over previous
//
#include <hip/hip_runtime.h>

#define EPS 1e-6f
#define NSTEPS 4
#define TPB 128
#define GROUPS 4          // 32-lane solve groups per block
#define TPG 2             // batch tiles solved simultaneously per group
#define TILES (GROUPS * TPG)   // 8 tiles resident in LDS per block
#define PITCH 33          // LDS row pitch (floats): bank-conflict-free transpose
#define TSTRIDE (32 * PITCH)

// ---------------------------------------------------------------------------
// Kernel 1: precompute Thomas coefficients per (step, c, solve-line).
// P[((s*3+c)*32 + i)*32 + lane] = float4(a_i, 1/denom_i, cs_i, 0)
// lane = h (x-dir) or w (y-dir); i = position along the solve direction.
// (Identical to the proven R1 version.)
// ---------------------------------------------------------------------------
__global__ void coeff_kernel(const float* __restrict__ ab,
                             const float* __restrict__ atc,
                             const float* __restrict__ bb,
                             const float* __restrict__ btc,
                             float4* __restrict__ PX,
                             float4* __restrict__ PY)
{
    int tid = blockIdx.x * blockDim.x + threadIdx.x;
    if (tid >= 768) return;                 // 2 dirs * 4 steps * 3 ch * 32 lanes
    int lane = tid & 31;
    int rest = tid >> 5;                    // 0..23
    int c    = rest % 3;
    int s    = (rest / 3) & 3;
    int dir  = rest / 12;                   // 0 = x, 1 = y
    float t  = 0.15f * (float)s;

    float A[32];
    float dt;
    if (dir == 0) {
        int h = lane;
        const float* pa = ab  + (c * 32 + h) * 32;
        const float* pt = atc + (c * 32 + h) * 32;
        #pragma unroll
        for (int w = 0; w < 32; w++)
            A[w] = fmaxf(pa[w] + t * pt[w], EPS);
        dt = 0.075f;                        // DT/2
    } else {
        int w = lane;
        #pragma unroll
        for (int h = 0; h < 32; h++)
            A[h] = fmaxf(bb[(c * 32 + h) * 32 + w] + t * btc[(c * 32 + h) * 32 + w], EPS);
        dt = 0.15f;                         // DT
    }

    // 3-tap mean with replicate padding
    float S[32];
    #pragma unroll
    for (int i = 0; i < 32; i++) {
        float l = A[(i == 0) ? 0 : i - 1];
        float r = A[(i == 31) ? 31 : i + 1];
        S[i] = (l + A[i] + r) / 3.0f;
    }

    float4* dst = (dir == 0 ? PX : PY) + ((s * 3 + c) * 32) * 32 + lane;
    float cp = 0.0f;
    for (int i = 0; i < 32; i++) {
        float co = S[i] * dt;               // coeff = smoothed * dt / DX^2 (DX=1)
        float a  = -co;
        float b  = (i == 0 || i == 31) ? (1.0f + co) : (1.0f + 2.0f * co);
        float cc = -co;
        float denom = (b - a * cp) + EPS;   // matches ref: eps added every step
        float inv = 1.0f / denom;           // precise division here (cheap)
        float cs  = cc / denom;
        if (i == 31) cs = 0.0f;             // ref zeroes c_star[N-1]
        dst[i * 32] = make_float4(a, inv, cs, 0.0f);
        cp = cs;
    }
}

// ---------------------------------------------------------------------------
// Kernel 2: fused 4-step ADI pipeline. R4 = R1 structure + ONE change:
// each 32-lane group solves TWO batch tiles (A,B) at once. Coefficients are
// shared across all batches, so the per-iteration float4 coefficient load is
// issued once and applied to two independent Thomas chains -> coefficient
// traffic/issue halves and the serial fma recurrence gets 2-way ILP.
// csr[] stays in registers (R3 showed reloading cs from global inside the
// backward chain is a regression). Arithmetic per element bitwise = R1.
// __launch_bounds__(128,2): 256-VGPR budget for valA+valB+csr (96 floats)
// + load pipelining; do NOT tighten (R0/R3 both spilled under tight caps).
// ---------------------------------------------------------------------------
__global__ __launch_bounds__(TPB, 2)
void diffuse_kernel(const float* __restrict__ u,
                    const float4* __restrict__ PX,
                    const float4* __restrict__ PY,
                    const float* __restrict__ coupling,
                    float* __restrict__ out)
{
    __shared__ float lds[TILES * TSTRIDE];

    const int tid = threadIdx.x;
    const int g   = tid >> 5;               // group within block (0..3)
    const int r   = tid & 31;               // lane within group
    // consecutive blocks share c: co-resident blocks keep the same 32 KB
    // coefficient slab hot in L1
    const int nper = gridDim.x / 3;         // blocks per channel
    const int c    = blockIdx.x / nper;
    const long grp = blockIdx.x % nper;
    const long bA  = grp * TILES + g * 2;   // batch of tile A
    const long baseA = (bA * 3 + c) << 10;  // 32*32 floats per (b,c) image
    const long baseB = baseA + 3072;        // batch bA+1, same c: +3*1024 floats

    float* TA = lds + (g * 2 + 0) * TSTRIDE;
    float* TB = lds + (g * 2 + 1) * TSTRIDE;

    // ---- stage global -> LDS (coalesced float4 per 32-lane group) ----
    const float4* sA = (const float4*)(u + baseA);
    const float4* sB = (const float4*)(u + baseB);
    #pragma unroll
    for (int j = 0; j < 8; j++) {
        float4 va = sA[j * 32 + r];
        float4 vb = sB[j * 32 + r];
        int f = (j * 32 + r) * 4;           // linear float index in tile
        int row = f >> 5, col = f & 31;
        float* pa = TA + row * PITCH + col;
        float* pb = TB + row * PITCH + col;
        pa[0] = va.x; pa[1] = va.y; pa[2] = va.z; pa[3] = va.w;
        pb[0] = vb.x; pb[1] = vb.y; pb[2] = vb.z; pb[3] = vb.w;
    }
    const float kc = coupling[c * 3 + c];
    __syncthreads();

    float valA[32], valB[32];
    float csr[32];

    #pragma unroll 1
    for (int s = 0; s < NSTEPS; s++) {
        const float4* px = PX + (s * 3 + c) * 1024;
        const float4* py = PY + (s * 3 + c) * 1024;

        // ---------- x half-step #1 (thread = row r) ----------
        {
            float dpA = 0.0f, dpB = 0.0f;
            #pragma unroll
            for (int i = 0; i < 32; i++) {
                float4 p  = px[i * 32 + r];
                float dA  = (s == 0) ? TA[r * PITCH + i] : valA[i];
                float dB  = (s == 0) ? TB[r * PITCH + i] : valB[i];
                dpA = (dA - p.x * dpA) * p.y;
                dpB = (dB - p.x * dpB) * p.y;
                valA[i] = dpA;
                valB[i] = dpB;
                csr[i]  = p.z;
            }
            float xA = 0.0f, xB = 0.0f;
            #pragma unroll
            for (int i = 31; i >= 0; i--) {
                xA = valA[i] - csr[i] * xA;
                xB = valB[i] - csr[i] * xB;
                TA[r * PITCH + i] = xA;     // expose rows for y transpose
                TB[r * PITCH + i] = xB;
            }
        }
        __syncthreads();

        // ---------- y full step (thread = col r) ----------
        {
            float dpA = 0.0f, dpB = 0.0f;
            #pragma unroll
            for (int i = 0; i < 32; i++) {
                float4 p  = py[i * 32 + r];
                float dA  = TA[i * PITCH + r];
                float dB  = TB[i * PITCH + r];
                dpA = (dA - p.x * dpA) * p.y;
                dpB = (dB - p.x * dpB) * p.y;
                valA[i] = dpA;
                valB[i] = dpB;
                csr[i]  = p.z;
            }
            float xA = 0.0f, xB = 0.0f;
            #pragma unroll
            for (int i = 31; i >= 0; i--) {
                xA = valA[i] - csr[i] * xA;
                xB = valB[i] - csr[i] * xB;
                TA[i * PITCH + r] = xA;     // expose cols for x transpose
                TB[i * PITCH + r] = xB;
            }
        }
        __syncthreads();

        // ---------- x half-step #2 (thread = row r), result + scale in regs ----------
        {
            float dpA = 0.0f, dpB = 0.0f;
            #pragma unroll
            for (int i = 0; i < 32; i++) {
                float4 p  = px[i * 32 + r];
                float dA  = TA[r * PITCH + i];
                float dB  = TB[r * PITCH + i];
                dpA = (dA - p.x * dpA) * p.y;
                dpB = (dB - p.x * dpB) * p.y;
                valA[i] = dpA;
                valB[i] = dpB;
                csr[i]  = p.z;
            }
            float xA = 0.0f, xB = 0.0f;
            #pragma unroll
            for (int i = 31; i >= 0; i--) {
                xA = valA[i] - csr[i] * xA;  // backward uses UNSCALED neighbor
                xB = valB[i] - csr[i] * xB;
                valA[i] = kc * xA;           // channel-diagonal scale
                valB[i] = kc * xB;
            }
        }
        // no barrier needed: x2 and next x1 touch only this thread's rows
    }

    // ---- write back: regs -> LDS rows -> coalesced global float4 ----
    #pragma unroll
    for (int i = 0; i < 32; i++) {
        TA[r * PITCH + i] = valA[i];
        TB[r * PITCH + i] = valB[i];
    }
    __syncthreads();

    float4* dA4 = (float4*)(out + baseA);
    float4* dB4 = (float4*)(out + baseB);
    #pragma unroll
    for (int j = 0; j < 8; j++) {
        int f = (j * 32 + r) * 4;
        int row = f >> 5, col = f & 31;
        float* pa = TA + row * PITCH + col;
        float* pb = TB + row * PITCH + col;
        dA4[j * 32 + r] = make_float4(pa[0], pa[1], pa[2], pa[3]);
        dB4[j * 32 + r] = make_float4(pb[0], pb[1], pb[2], pb[3]);
    }
}

// ---------------------------------------------------------------------------
extern "C" void kernel_launch(void* const* d_in, const int* in_sizes, int n_in,
                              void* d_out, int out_size, void* d_ws, size_t ws_size,
                              hipStream_t stream) {
    const float* u   = (const float*)d_in[0];
    const float* ab  = (const float*)d_in[1];  // alpha_base
    const float* bb  = (const float*)d_in[2];  // beta_base
    const float* atc = (const float*)d_in[3];  // alpha_time_coeff
    const float* btc = (const float*)d_in[4];  // beta_time_coeff
    const float* cpl = (const float*)d_in[5];  // channel_coupling [3][3]
    float* out = (float*)d_out;

    // workspace: PX (192 KB) then PY (192 KB)
    float4* PX = (float4*)d_ws;
    float4* PY = PX + 4 * 3 * 32 * 32;

    coeff_kernel<<<3, 256, 0, stream>>>(ab, atc, bb, btc, PX, PY);

    int B = in_sizes[0] / (3 * 32 * 32);       // 16384
    int nblocks = (B / TILES) * 3;             // 6144 blocks of 8 tiles
    diffuse_kernel<<<nblocks, TPB, 0, stream>>>(u, PX, PY, cpl, out);
}